// Round 9
// baseline (199.543 us; speedup 1.0000x reference)
//
#include <hip/hip_runtime.h>
#include <hip/hip_bf16.h>
#include <math.h>

#define NT 16
#define NR 8
#define PD 32
#define HG 48
#define WG 48
#define NB 8
#define CH 96
#define HW 384
#define XHW (HW * HW)
#define S8 0.70710678118654752f
#define FEAT0 8192  // ushort offset of feat buffer in ws

typedef short short8 __attribute__((ext_vector_type(8)));
typedef float f32x4 __attribute__((ext_vector_type(4)));

static __device__ const float CT16[16] = {
    1.0f, 0.9238795325112867f, 0.7071067811865476f, 0.3826834323650898f,
    0.0f, -0.3826834323650898f, -0.7071067811865476f, -0.9238795325112867f,
    -1.0f, -0.9238795325112867f, -0.7071067811865476f, -0.3826834323650898f,
    0.0f, 0.3826834323650898f, 0.7071067811865476f, 0.9238795325112867f};
static __device__ const float ST16[16] = {
    0.0f, 0.3826834323650898f, 0.7071067811865476f, 0.9238795325112867f,
    1.0f, 0.9238795325112867f, 0.7071067811865476f, 0.3826834323650898f,
    0.0f, -0.3826834323650898f, -0.7071067811865476f, -0.9238795325112867f,
    -1.0f, -0.9238795325112867f, -0.7071067811865476f, -0.3826834323650898f};

static __device__ __forceinline__ unsigned short f2bf(float f) {
  unsigned int u = __float_as_uint(f);
  u = u + 0x7fffu + ((u >> 16) & 1u);
  return (unsigned short)(u >> 16);
}
static __device__ __forceinline__ unsigned int pk2bf(float a, float b) {
  union { __hip_bfloat162 h; unsigned int u; } c;
  c.h = __float22bfloat162_rn(make_float2(a, b));
  return c.u;
}
static __device__ __forceinline__ float bf2f_lo(unsigned int v) {
  return __uint_as_float(v << 16);
}
static __device__ __forceinline__ float bf2f_hi(unsigned int v) {
  return __uint_as_float(v & 0xffff0000u);
}

#define MAGR(x_) log1pf(0.125f * fabsf(x_))
#define MAGC(re_, im_) log1pf(0.125f * sqrtf((re_) * (re_) + (im_) * (im_)))

// ws layout (ushort units): [0..3071] W B-fragments (6 frags x 64 lanes x 8),
// [3072..4095] G B-fragments, [FEAT0..] feat bf16:
// feat[(b*48+hy)*8 + r][win 48][och 32][px 8]  (12288 ushorts per r-block)
__global__ void lpp_setup(const float* __restrict__ Wp,
                          unsigned short* __restrict__ ws) {
  int gt = blockIdx.x * 256 + threadIdx.x;
  if (gt < 384) {  // W fragments: B[k][n] = W[n*96+k], bf16
    int f = gt >> 6, l = gt & 63;
    int ks = f >> 1, nt = f & 1;
    int n = nt * 16 + (l & 15);
    int kbase = ks * 32 + (l >> 4) * 8;
    for (int jj = 0; jj < 8; ++jj)
      ws[(f * 64 + l) * 8 + jj] = f2bf(Wp[n * CH + kbase + jj]);
  }
  if (gt >= 1024 && gt < 2048) {  // dense polar matrix G[j][t]
    int q = gt - 1024;
    int j = q >> 4, t = q & 15;
    float g = 0.f;
    for (int r = 0; r < 8; ++r) {
      float rad = (float)r / 7.0f;
      float px = (rad * CT16[t] + 1.0f) * 3.5f;
      float py = (rad * ST16[t] + 1.0f) * 3.5f;
      float xf = floorf(px), yf = floorf(py);
      float wx = px - xf, wy = py - yf;
      int ix = (int)xf, iy = (int)yf;
      int xi0 = min(max(ix, 0), 7), xi1 = min(max(ix + 1, 0), 7);
      int yi0 = min(max(iy, 0), 7), yi1 = min(max(iy + 1, 0), 7);
      bool vx0 = (ix >= 0) && (ix < 8), vx1 = (ix + 1 >= 0) && (ix + 1 < 8);
      bool vy0 = (iy >= 0) && (iy < 8), vy1 = (iy + 1 >= 0) && (iy + 1 < 8);
      float w0 = (vx0 && vy0) ? (1.f - wx) * (1.f - wy) : 0.f;
      float w1 = (vx1 && vy0) ? wx * (1.f - wy) : 0.f;
      float w2 = (vx0 && vy1) ? (1.f - wx) * wy : 0.f;
      float w3 = (vx1 && vy1) ? wx * wy : 0.f;
      if (yi0 * 8 + xi0 == j) g += w0;
      if (yi0 * 8 + xi1 == j) g += w1;
      if (yi1 * 8 + xi0 == j) g += w2;
      if (yi1 * 8 + xi1 == j) g += w3;
    }
    int f = j >> 5, kc = (j >> 3) & 3, jj = j & 7;
    int l = (kc << 4) | t;
    ws[3072 + (f * 64 + l) * 8 + jj] = f2bf(g);
  }
}

// K1: projection. Block = (b, hy): 48 windows x 8 rows. Internal loop over
// the 8 rows; per row stage all 96 channels (1536B each) into LDS, MFMA the
// row's feat contribution with transient accumulators, store coalesced.
// Per channel the block reads 8 back-to-back 1536B bursts = 12KB sequential
// stream (DRAM row locality). Next row's first 12 float4 prefetched across
// the MFMA phase (T14).
__global__ __launch_bounds__(256, 2) void lpp_proj(
    const float* __restrict__ x, const float* __restrict__ bp,
    const unsigned short* __restrict__ wsc, unsigned short* __restrict__ wsf) {
  __shared__ unsigned short sx[96 * 386];  // 74.1 KB, [ch][px] stride 386

  const int tid = threadIdx.x;
  const int lane = tid & 63;
  const int l15 = lane & 15;
  const int kcA = lane >> 4;
  const int w = tid >> 6;
  const int gid = blockIdx.x;
  const int hy = gid % HG;
  const int b = gid / HG;
  const short8* wsV = (const short8*)wsc;

  short8 bfr[6];
#pragma unroll
  for (int f = 0; f < 6; ++f) bfr[f] = wsV[f * 64 + lane];
  const float bs0 = bp[l15];
  const float bs1 = bp[16 + l15];

  const float* xb = x + (size_t)b * CH * XHW + (size_t)(hy * 8) * HW;
  // wave stages channels [w*24, w*24+24): flat f = i*64+lane over
  // 24ch x 96 float4; ch = w*24 + f/96, off = f%96 (16B units in row)

  float4 lv[12];
#pragma unroll
  for (int i = 0; i < 12; ++i) {
    int f = i * 64 + lane;
    int ch = w * 24 + f / 96, off = f - (f / 96) * 96;
    lv[i] = *(const float4*)(xb + (size_t)ch * XHW + off * 4);
  }

  for (int r = 0; r < 8; ++r) {
    // ---- staging: consume 36 float4, keep 12 in flight (rolls into r+1) ----
#pragma unroll
    for (int i = 0; i < 36; ++i) {
      float4 v = lv[i % 12];
      int f = i * 64 + lane;
      int ch = w * 24 + f / 96, off = f - (f / 96) * 96;
      uint2 pw;
      pw.x = pk2bf(v.x, v.y);
      pw.y = pk2bf(v.z, v.w);
      *(uint2*)&sx[ch * 386 + off * 4] = pw;
      int ni = i + 12;
      if (ni < 36) {
        int nf = ni * 64 + lane;
        int nch = w * 24 + nf / 96, noff = nf - (nf / 96) * 96;
        lv[ni % 12] =
            *(const float4*)(xb + (size_t)nch * XHW + (size_t)r * HW + noff * 4);
      } else if (r < 7) {
        int nf = (ni - 36) * 64 + lane;
        int nch = w * 24 + nf / 96, noff = nf - (nf / 96) * 96;
        lv[ni % 12] = *(const float4*)(xb + (size_t)nch * XHW +
                                       (size_t)(r + 1) * HW + noff * 4);
      }
    }
    __syncthreads();

    // ---- MFMA + coalesced feat store (lv holds r+1 loads through this) ----
    unsigned short* fb =
        wsf + FEAT0 + (size_t)((b * HG + hy) * 8 + r) * 12288;
#pragma unroll
    for (int tt = 0; tt < 6; ++tt) {
      int mt = w * 6 + tt;  // px-tile: pixels mt*16 .. mt*16+15
      f32x4 a0v = (f32x4){0.f, 0.f, 0.f, 0.f};
      f32x4 a1v = (f32x4){0.f, 0.f, 0.f, 0.f};
#pragma unroll
      for (int ks = 0; ks < 3; ++ks) {
        union { unsigned short h[8]; short8 v; } a;
#pragma unroll
        for (int j = 0; j < 8; ++j)
          a.h[j] = sx[(ks * 32 + kcA * 8 + j) * 386 + mt * 16 + l15];
        a0v = __builtin_amdgcn_mfma_f32_16x16x32_bf16(a.v, bfr[ks * 2 + 0],
                                                      a0v, 0, 0, 0);
        a1v = __builtin_amdgcn_mfma_f32_16x16x32_bf16(a.v, bfr[ks * 2 + 1],
                                                      a1v, 0, 0, 0);
      }
      // C layout: o = lane&15 (+16 for a1v), px16 = 4*(lane>>4)+reg
      // win = mt*2 + (lane>>5), px-in-win = 4*((lane>>4)&1) + reg
      int base = (mt * 2 + (lane >> 5)) * 256 + (((lane >> 4) & 1) << 2);
      uint2 s0, s1;
      s0.x = pk2bf(a0v[0] + bs0, a0v[1] + bs0);
      s0.y = pk2bf(a0v[2] + bs0, a0v[3] + bs0);
      s1.x = pk2bf(a1v[0] + bs1, a1v[1] + bs1);
      s1.y = pk2bf(a1v[2] + bs1, a1v[3] + bs1);
      *(uint2*)&fb[base + l15 * 8] = s0;
      *(uint2*)&fb[base + (16 + l15) * 8] = s1;
    }
    __syncthreads();
  }
}

// K2: FFT + polar + softmax. Reads feat bf16 from ws straight to registers.
__global__ __launch_bounds__(256, 4) void lpp_fft(
    const unsigned short* __restrict__ ws, float* __restrict__ out) {
  __shared__ short8 ldsX[2048];  // 32KB mag planes (G A-fragment layout)
  __shared__ float obuf[144];

  const int tid = threadIdx.x;
  const int lane = tid & 63;
  const int wave = tid >> 6;
  const int gid = blockIdx.x;
  const int wxg = gid % 6;
  const int hy = (gid / 6) % HG;
  const int b = gid / (6 * HG);
  const short8* wsV = (const short8*)ws;
  const int kcA = lane >> 4;

  // ---- load own plane (win8 = tid>>5, o = tid&31): 8 rows x 16B ----
  {
    const int win8 = tid >> 5, o = tid & 31;
    const size_t rbase = (size_t)(b * HG + hy) * 8;
    const int poff = ((wxg * 8 + win8) * 32 + o) * 8;
    uint4 fr[8];
#pragma unroll
    for (int r = 0; r < 8; ++r)
      fr[r] = *(const uint4*)&ws[FEAT0 + (rbase + r) * 12288 + poff];

    float rr[8][8];
#pragma unroll
    for (int k = 0; k < 8; ++k) {
      float v[8];
      v[0] = bf2f_lo(fr[k].x); v[1] = bf2f_hi(fr[k].x);
      v[2] = bf2f_lo(fr[k].y); v[3] = bf2f_hi(fr[k].y);
      v[4] = bf2f_lo(fr[k].z); v[5] = bf2f_hi(fr[k].z);
      v[6] = bf2f_lo(fr[k].w); v[7] = bf2f_hi(fr[k].w);
      float a0 = v[0] + v[4], a1 = v[0] - v[4], a2 = v[2] + v[6], a3 = v[2] - v[6];
      float b0 = v[1] + v[5], b1 = v[1] - v[5], b2 = v[3] + v[7], b3 = v[3] - v[7];
      float e0 = a0 + a2, e2 = a0 - a2, o0 = b0 + b2, o2 = b0 - b2;
      float t1 = S8 * (b1 - b3), t2 = S8 * (b1 + b3);
      rr[k][0] = e0 + o0; rr[k][1] = e0 - o0;
      rr[k][2] = a1 + t1; rr[k][3] = -a3 - t2;
      rr[k][4] = e2;      rr[k][5] = -o2;
      rr[k][6] = a1 - t1; rr[k][7] = a3 - t2;
    }
    float mg0[5], mg4[5], mg1[8], mg2[8], mg3[8];
#define REALCOL(SLOT, OUT)                                                    \
  {                                                                           \
    float a0 = rr[0][SLOT] + rr[4][SLOT], a1 = rr[0][SLOT] - rr[4][SLOT];     \
    float a2 = rr[2][SLOT] + rr[6][SLOT], a3 = rr[2][SLOT] - rr[6][SLOT];     \
    float b0 = rr[1][SLOT] + rr[5][SLOT], b1 = rr[1][SLOT] - rr[5][SLOT];     \
    float b2 = rr[3][SLOT] + rr[7][SLOT], b3 = rr[3][SLOT] - rr[7][SLOT];     \
    float e0 = a0 + a2, e2 = a0 - a2, o0 = b0 + b2, o2 = b0 - b2;             \
    float t1 = S8 * (b1 - b3), t2 = S8 * (b1 + b3);                           \
    OUT[0] = MAGR(e0 + o0); OUT[4] = MAGR(e0 - o0);                           \
    OUT[1] = MAGC(a1 + t1, -a3 - t2);                                         \
    OUT[2] = MAGC(e2, -o2);                                                   \
    OUT[3] = MAGC(a1 - t1, a3 - t2);                                          \
  }
#define CPLXCOL(SR, SI, OUT)                                                  \
  {                                                                           \
    float t0r = rr[0][SR] + rr[4][SR], t0i = rr[0][SI] + rr[4][SI];           \
    float t1r = rr[0][SR] - rr[4][SR], t1i = rr[0][SI] - rr[4][SI];           \
    float t2r = rr[2][SR] + rr[6][SR], t2i = rr[2][SI] + rr[6][SI];           \
    float t3r = rr[2][SR] - rr[6][SR], t3i = rr[2][SI] - rr[6][SI];           \
    float E0r = t0r + t2r, E0i = t0i + t2i, E2r = t0r - t2r, E2i = t0i - t2i; \
    float E1r = t1r + t3i, E1i = t1i - t3r, E3r = t1r - t3i, E3i = t1i + t3r; \
    float u0r = rr[1][SR] + rr[5][SR], u0i = rr[1][SI] + rr[5][SI];           \
    float u1r = rr[1][SR] - rr[5][SR], u1i = rr[1][SI] - rr[5][SI];           \
    float u2r = rr[3][SR] + rr[7][SR], u2i = rr[3][SI] + rr[7][SI];           \
    float u3r = rr[3][SR] - rr[7][SR], u3i = rr[3][SI] - rr[7][SI];           \
    float O0r = u0r + u2r, O0i = u0i + u2i, O2r = u0r - u2r, O2i = u0i - u2i; \
    float O1r = u1r + u3i, O1i = u1i - u3r, O3r = u1r - u3i, O3i = u1i + u3r; \
    float W1r = S8 * (O1r + O1i), W1i = S8 * (O1i - O1r);                     \
    float W2r = O2i, W2i = -O2r;                                              \
    float W3r = S8 * (O3i - O3r), W3i = -S8 * (O3r + O3i);                    \
    OUT[0] = MAGC(E0r + O0r, E0i + O0i); OUT[4] = MAGC(E0r - O0r, E0i - O0i); \
    OUT[1] = MAGC(E1r + W1r, E1i + W1i); OUT[5] = MAGC(E1r - W1r, E1i - W1i); \
    OUT[2] = MAGC(E2r + W2r, E2i + W2i); OUT[6] = MAGC(E2r - W2r, E2i - W2i); \
    OUT[3] = MAGC(E3r + W3r, E3i + W3i); OUT[7] = MAGC(E3r - W3r, E3i - W3i); \
  }
    REALCOL(0, mg0)
    REALCOL(1, mg4)
    CPLXCOL(2, 3, mg1)
    CPLXCOL(4, 5, mg2)
    CPLXCOL(6, 7, mg3)
    // hermitian expand + fftshift, packed bf16x8 into G A-fragment layout
    const int pb8 = tid * 8, p7 = tid & 7;
#pragma unroll
    for (int up = 0; up < 8; ++up) {
      union { unsigned short h[8]; short8 v; } pk;
#pragma unroll
      for (int vp = 0; vp < 8; ++vp) {
        const int u = (up + 4) & 7, vx = (vp + 4) & 7;
        float m;
        if (vx == 0)      m = mg0[(u <= 4) ? u : (8 - u)];
        else if (vx == 4) m = mg4[(u <= 4) ? u : (8 - u)];
        else if (vx == 1) m = mg1[u];
        else if (vx == 2) m = mg2[u];
        else if (vx == 3) m = mg3[u];
        else { const int uu = (8 - u) & 7;
               m = (vx == 5) ? mg3[uu] : (vx == 6) ? mg2[uu] : mg1[uu]; }
        pk.h[vp] = f2bf(m);
      }
      ldsX[pb8 + (up ^ p7)] = pk.v;
    }
  }
  __syncthreads();

  // ---- polar sampling + radial sum as MFMA: psum = mag(256x64) * G(64x16) ----
  {
    short8 gf0 = wsV[384 + lane];
    short8 gf1 = wsV[448 + lane];
    f32x4 ag[4];
#pragma unroll
    for (int pt = 0; pt < 4; ++pt) {
      int prow = (wave * 4 + pt) * 16 + (lane & 15);
      int p7 = prow & 7, pb = prow * 8;
      short8 a0 = ldsX[pb + (kcA ^ p7)];
      short8 a1 = ldsX[pb + ((kcA + 4) ^ p7)];
      f32x4 zf = (f32x4){0.f, 0.f, 0.f, 0.f};
      zf = __builtin_amdgcn_mfma_f32_16x16x32_bf16(a0, gf0, zf, 0, 0, 0);
      zf = __builtin_amdgcn_mfma_f32_16x16x32_bf16(a1, gf1, zf, 0, 0, 0);
      ag[pt] = zf;
    }
    float s0 = ag[0][0] + ag[0][1] + ag[0][2] + ag[0][3] +
               ag[1][0] + ag[1][1] + ag[1][2] + ag[1][3];
    float s1 = ag[2][0] + ag[2][1] + ag[2][2] + ag[2][3] +
               ag[3][0] + ag[3][1] + ag[3][2] + ag[3][3];
    s0 += __shfl_xor(s0, 16); s0 += __shfl_xor(s0, 32);
    s1 += __shfl_xor(s1, 16); s1 += __shfl_xor(s1, 32);
    float l0 = s0 * (1.0f / 256.0f), l1 = s1 * (1.0f / 256.0f);
    float m0 = l0, m1 = l1;
#pragma unroll
    for (int mk = 1; mk < 16; mk <<= 1) {
      m0 = fmaxf(m0, __shfl_xor(m0, mk));
      m1 = fmaxf(m1, __shfl_xor(m1, mk));
    }
    float e0 = expf(l0 - m0), e1 = expf(l1 - m1);
    float ss0 = e0, ss1 = e1;
#pragma unroll
    for (int mk = 1; mk < 16; mk <<= 1) {
      ss0 += __shfl_xor(ss0, mk);
      ss1 += __shfl_xor(ss1, mk);
    }
    float d0 = e0 / ss0, d1 = e1 / ss1;
    float h0 = -d0 * logf(fmaxf(d0, 1e-8f));
    float h1 = -d1 * logf(fmaxf(d1, 1e-8f));
#pragma unroll
    for (int mk = 1; mk < 16; mk <<= 1) {
      h0 += __shfl_xor(h0, mk);
      h1 += __shfl_xor(h1, mk);
    }
    float c0 = fminf(fmaxf(1.f - h0 * (1.0f / 2.7725887222397811f), 0.f), 1.f);
    float c1 = fminf(fmaxf(1.f - h1 * (1.0f / 2.7725887222397811f), 0.f), 1.f);
    if (lane < 16) {
      obuf[wave * 32 + lane] = d0;
      obuf[wave * 32 + 16 + lane] = d1;
    }
    if (lane == 0) {
      obuf[128 + wave * 2] = c0;
      obuf[128 + wave * 2 + 1] = c1;
    }
  }
  __syncthreads();

  if (tid < 128) {
    int t = tid >> 3, win = tid & 7;
    int wx = wxg * 8 + win;
    out[((size_t)(b * NT + t) * HG + hy) * WG + wx] = obuf[win * 16 + t];
  } else if (tid < 136) {
    int win = tid - 128;
    int wx = wxg * 8 + win;
    out[(size_t)NB * NT * HG * WG + ((size_t)b * HG + hy) * WG + wx] =
        obuf[128 + win];
  }
}

extern "C" void kernel_launch(void* const* d_in, const int* in_sizes, int n_in,
                              void* d_out, int out_size, void* d_ws,
                              size_t ws_size, hipStream_t stream) {
  (void)in_sizes; (void)n_in; (void)ws_size; (void)out_size;
  const float* x = (const float*)d_in[0];
  const float* Wp = (const float*)d_in[1];
  const float* bp = (const float*)d_in[2];
  unsigned short* ws = (unsigned short*)d_ws;
  float* out = (float*)d_out;
  lpp_setup<<<8, 256, 0, stream>>>(Wp, ws);
  lpp_proj<<<NB * HG, 256, 0, stream>>>(x, bp, ws, ws);
  lpp_fft<<<NB * HG * 6, 256, 0, stream>>>(ws, out);
}

// Round 10
// 136.510 us; speedup vs baseline: 1.4617x; 1.4617x over previous
//
#include <hip/hip_runtime.h>
#include <hip/hip_bf16.h>
#include <math.h>

#define NT 16
#define NR 8
#define PD 32
#define HG 48
#define WG 48
#define NB 8
#define CH 96
#define HW 384
#define XHW (HW * HW)
#define S8 0.70710678118654752f

typedef short short8 __attribute__((ext_vector_type(8)));
typedef float f32x4 __attribute__((ext_vector_type(4)));

static __device__ const float CT16[16] = {
    1.0f, 0.9238795325112867f, 0.7071067811865476f, 0.3826834323650898f,
    0.0f, -0.3826834323650898f, -0.7071067811865476f, -0.9238795325112867f,
    -1.0f, -0.9238795325112867f, -0.7071067811865476f, -0.3826834323650898f,
    0.0f, 0.3826834323650898f, 0.7071067811865476f, 0.9238795325112867f};
static __device__ const float ST16[16] = {
    0.0f, 0.3826834323650898f, 0.7071067811865476f, 0.9238795325112867f,
    1.0f, 0.9238795325112867f, 0.7071067811865476f, 0.3826834323650898f,
    0.0f, -0.3826834323650898f, -0.7071067811865476f, -0.9238795325112867f,
    -1.0f, -0.9238795325112867f, -0.7071067811865476f, -0.3826834323650898f};

static __device__ __forceinline__ unsigned short f2bf(float f) {
  unsigned int u = __float_as_uint(f);
  u = u + 0x7fffu + ((u >> 16) & 1u);
  return (unsigned short)(u >> 16);
}
static __device__ __forceinline__ unsigned int pk2bf(float a, float b) {
  union { __hip_bfloat162 h; unsigned int u; } c;
  c.h = __float22bfloat162_rn(make_float2(a, b));
  return c.u;
}
static __device__ __forceinline__ float bf2f_lo(unsigned int v) {
  return __uint_as_float(v << 16);
}
static __device__ __forceinline__ float bf2f_hi(unsigned int v) {
  return __uint_as_float(v & 0xffff0000u);
}

#define MAGR(x_) log1pf(0.125f * fabsf(x_))
#define MAGC(re_, im_) log1pf(0.125f * sqrtf((re_) * (re_) + (im_) * (im_)))

// ws layout (ushort units): [0..3071] W B-fragments (6 frags x 64 lanes x 8),
// [3072..4095] G B-fragments (2 frags x 64 lanes x 8).
__global__ void lpp_setup(const float* __restrict__ Wp,
                          unsigned short* __restrict__ ws) {
  int gt = blockIdx.x * 256 + threadIdx.x;
  if (gt < 384) {  // W fragments: B[k][n] = W[n*96+k], bf16
    int f = gt >> 6, l = gt & 63;
    int ks = f >> 1, nt = f & 1;
    int n = nt * 16 + (l & 15);
    int kbase = ks * 32 + (l >> 4) * 8;
    for (int jj = 0; jj < 8; ++jj)
      ws[(f * 64 + l) * 8 + jj] = f2bf(Wp[n * CH + kbase + jj]);
  }
  if (gt >= 1024 && gt < 2048) {  // dense polar matrix G[j][t]
    int q = gt - 1024;
    int j = q >> 4, t = q & 15;
    float g = 0.f;
    for (int r = 0; r < 8; ++r) {
      float rad = (float)r / 7.0f;
      float px = (rad * CT16[t] + 1.0f) * 3.5f;
      float py = (rad * ST16[t] + 1.0f) * 3.5f;
      float xf = floorf(px), yf = floorf(py);
      float wx = px - xf, wy = py - yf;
      int ix = (int)xf, iy = (int)yf;
      int xi0 = min(max(ix, 0), 7), xi1 = min(max(ix + 1, 0), 7);
      int yi0 = min(max(iy, 0), 7), yi1 = min(max(iy + 1, 0), 7);
      bool vx0 = (ix >= 0) && (ix < 8), vx1 = (ix + 1 >= 0) && (ix + 1 < 8);
      bool vy0 = (iy >= 0) && (iy < 8), vy1 = (iy + 1 >= 0) && (iy + 1 < 8);
      float w0 = (vx0 && vy0) ? (1.f - wx) * (1.f - wy) : 0.f;
      float w1 = (vx1 && vy0) ? wx * (1.f - wy) : 0.f;
      float w2 = (vx0 && vy1) ? (1.f - wx) * wy : 0.f;
      float w3 = (vx1 && vy1) ? wx * wy : 0.f;
      if (yi0 * 8 + xi0 == j) g += w0;
      if (yi0 * 8 + xi1 == j) g += w1;
      if (yi1 * 8 + xi0 == j) g += w2;
      if (yi1 * 8 + xi1 == j) g += w3;
    }
    int f = j >> 5, kc = (j >> 3) & 3, jj = j & 7;
    int l = (kc << 4) | t;
    ws[3072 + (f * 64 + l) * 8 + jj] = f2bf(g);
  }
}

__global__ __launch_bounds__(256, 4) void lpp_main(
    const float* __restrict__ x, const float* __restrict__ bp,
    const unsigned short* __restrict__ ws, float* __restrict__ out) {
  // 32KB, triple-purpose: x A-staging -> feat planes -> mag A-fragments
  __shared__ short8 ldsX[2048];
  __shared__ float obuf[144];
  unsigned int* ldsU = (unsigned int*)ldsX;

  const int tid = threadIdx.x;
  const int lane = tid & 63;
  const int wave = tid >> 6;
  // XCD chunked swizzle (bijective: 2304 = 8 * 288): each XCD gets one
  // contiguous batch image -> cross-block DRAM page locality per L2.
  const int bid = blockIdx.x;
  const int gid = (bid & 7) * 288 + (bid >> 3);
  const int wxg = gid % 6;
  const int hy = (gid / 6) % HG;
  const int b = gid / (6 * HG);
  const short8* wsV = (const short8*)ws;

  f32x4 acc[8][2];
#pragma unroll
  for (int m = 0; m < 8; ++m) {
    acc[m][0] = (f32x4){0.f, 0.f, 0.f, 0.f};
    acc[m][1] = (f32x4){0.f, 0.f, 0.f, 0.f};
  }

  const size_t xcb = (size_t)b * CH * XHW;
  const int kcA = lane >> 4;  // A-fragment k-chunk
  // ---- projection: 3 K-chunks of 32 ch, staged fp32->bf16 into LDS ----
  for (int ks = 0; ks < 3; ++ks) {
    if (ks) __syncthreads();  // prior MFMA done with ldsX
#pragma unroll
    for (int g2 = 0; g2 < 2; ++g2) {
      int id = tid + 256 * g2;
      int kc = id >> 7;
      int p0 = (id & 127) << 2;           // 4-aligned pixel base
      int row = (p0 >> 3) & 7;
      int gcol = wxg * 64 + ((p0 >> 6) << 3) + (p0 & 7);
      const float* xp = x + xcb + (size_t)(ks * 32 + kc * 8) * XHW +
                        (size_t)(hy * 8 + row) * HW + gcol;
      float q[8][4];
#pragma unroll
      for (int jj = 0; jj < 8; ++jj) {
        float4 v = *(const float4*)(xp + (size_t)jj * XHW);
        q[jj][0] = v.x; q[jj][1] = v.y; q[jj][2] = v.z; q[jj][3] = v.w;
      }
      int z = (p0 >> 3) & 7;
      int base3 = kc * 512 + (p0 & ~7);
#pragma unroll
      for (int i = 0; i < 4; ++i) {
        union { unsigned int u[4]; short8 v; } pk;
#pragma unroll
        for (int k2 = 0; k2 < 4; ++k2)
          pk.u[k2] = pk2bf(q[2 * k2][i], q[2 * k2 + 1][i]);
        int u = base3 | ((((p0 & 4) | i)) ^ z);
        ldsX[u] = pk.v;
      }
    }
    __syncthreads();
    short8 b0 = wsV[(ks * 2 + 0) * 64 + lane];
    short8 b1 = wsV[(ks * 2 + 1) * 64 + lane];
    int prow = wave * 128 + (lane & 15);
#pragma unroll
    for (int m = 0; m < 8; ++m) {
      int p = prow + m * 16;
      int s = kcA * 512 + p;
      short8 a = ldsX[s ^ ((p >> 3) & 7)];
      acc[m][0] = __builtin_amdgcn_mfma_f32_16x16x32_bf16(a, b0, acc[m][0], 0, 0, 0);
      acc[m][1] = __builtin_amdgcn_mfma_f32_16x16x32_bf16(a, b1, acc[m][1], 0, 0, 0);
    }
  }
  __syncthreads();

  // ---- scatter feat (C layout: col=lane&15, row=4*(lane>>4)+reg) ----
  {
    const float bias0 = bp[lane & 15];
    const float bias1 = bp[16 + (lane & 15)];
    int jb = (lane >> 4) << 2;
#pragma unroll
    for (int m = 0; m < 8; ++m) {
      int win = 2 * wave + (m >> 2);
      int j0 = ((m & 3) << 4) + jb;
#pragma unroll
      for (int nt = 0; nt < 2; ++nt) {
        int p = win * 32 + nt * 16 + (lane & 15);
        float bs = nt ? bias1 : bias0;
        int sh = (p & 15) << 1;
        int dwb = p * 32;
        unsigned int w0 = pk2bf(acc[m][nt][0] + bs, acc[m][nt][1] + bs);
        unsigned int w1 = pk2bf(acc[m][nt][2] + bs, acc[m][nt][3] + bs);
        ldsU[dwb + ((j0 >> 1) ^ sh)] = w0;
        ldsU[dwb + (((j0 >> 1) + 1) ^ sh)] = w1;
      }
    }
  }
  __syncthreads();

  // ---- per-thread 8x8 real FFT -> shifted log-magnitude ----
  {
    const int p = tid;
    const int sh = (p & 15) << 1;
    const int dwb = p * 32;
    float rr[8][8];
#pragma unroll
    for (int k = 0; k < 8; ++k) {
      float v[8];
#pragma unroll
      for (int i = 0; i < 4; ++i) {
        unsigned int u = ldsU[dwb + ((k * 4 + i) ^ sh)];
        v[2 * i] = bf2f_lo(u);
        v[2 * i + 1] = bf2f_hi(u);
      }
      float a0 = v[0] + v[4], a1 = v[0] - v[4], a2 = v[2] + v[6], a3 = v[2] - v[6];
      float b0 = v[1] + v[5], b1 = v[1] - v[5], b2 = v[3] + v[7], b3 = v[3] - v[7];
      float e0 = a0 + a2, e2 = a0 - a2, o0 = b0 + b2, o2 = b0 - b2;
      float t1 = S8 * (b1 - b3), t2 = S8 * (b1 + b3);
      rr[k][0] = e0 + o0; rr[k][1] = e0 - o0;
      rr[k][2] = a1 + t1; rr[k][3] = -a3 - t2;
      rr[k][4] = e2;      rr[k][5] = -o2;
      rr[k][6] = a1 - t1; rr[k][7] = a3 - t2;
    }
    float mg0[5], mg4[5], mg1[8], mg2[8], mg3[8];
#define REALCOL(SLOT, OUT)                                                    \
  {                                                                           \
    float a0 = rr[0][SLOT] + rr[4][SLOT], a1 = rr[0][SLOT] - rr[4][SLOT];     \
    float a2 = rr[2][SLOT] + rr[6][SLOT], a3 = rr[2][SLOT] - rr[6][SLOT];     \
    float b0 = rr[1][SLOT] + rr[5][SLOT], b1 = rr[1][SLOT] - rr[5][SLOT];     \
    float b2 = rr[3][SLOT] + rr[7][SLOT], b3 = rr[3][SLOT] - rr[7][SLOT];     \
    float e0 = a0 + a2, e2 = a0 - a2, o0 = b0 + b2, o2 = b0 - b2;             \
    float t1 = S8 * (b1 - b3), t2 = S8 * (b1 + b3);                           \
    OUT[0] = MAGR(e0 + o0); OUT[4] = MAGR(e0 - o0);                           \
    OUT[1] = MAGC(a1 + t1, -a3 - t2);                                         \
    OUT[2] = MAGC(e2, -o2);                                                   \
    OUT[3] = MAGC(a1 - t1, a3 - t2);                                          \
  }
#define CPLXCOL(SR, SI, OUT)                                                  \
  {                                                                           \
    float t0r = rr[0][SR] + rr[4][SR], t0i = rr[0][SI] + rr[4][SI];           \
    float t1r = rr[0][SR] - rr[4][SR], t1i = rr[0][SI] - rr[4][SI];           \
    float t2r = rr[2][SR] + rr[6][SR], t2i = rr[2][SI] + rr[6][SI];           \
    float t3r = rr[2][SR] - rr[6][SR], t3i = rr[2][SI] - rr[6][SI];           \
    float E0r = t0r + t2r, E0i = t0i + t2i, E2r = t0r - t2r, E2i = t0i - t2i; \
    float E1r = t1r + t3i, E1i = t1i - t3r, E3r = t1r - t3i, E3i = t1i + t3r; \
    float u0r = rr[1][SR] + rr[5][SR], u0i = rr[1][SI] + rr[5][SI];           \
    float u1r = rr[1][SR] - rr[5][SR], u1i = rr[1][SI] - rr[5][SI];           \
    float u2r = rr[3][SR] + rr[7][SR], u2i = rr[3][SI] + rr[7][SI];           \
    float u3r = rr[3][SR] - rr[7][SR], u3i = rr[3][SI] - rr[7][SI];           \
    float O0r = u0r + u2r, O0i = u0i + u2i, O2r = u0r - u2r, O2i = u0i - u2i; \
    float O1r = u1r + u3i, O1i = u1i - u3r, O3r = u1r - u3i, O3i = u1i + u3r; \
    float W1r = S8 * (O1r + O1i), W1i = S8 * (O1i - O1r);                     \
    float W2r = O2i, W2i = -O2r;                                              \
    float W3r = S8 * (O3i - O3r), W3i = -S8 * (O3r + O3i);                    \
    OUT[0] = MAGC(E0r + O0r, E0i + O0i); OUT[4] = MAGC(E0r - O0r, E0i - O0i); \
    OUT[1] = MAGC(E1r + W1r, E1i + W1i); OUT[5] = MAGC(E1r - W1r, E1i - W1i); \
    OUT[2] = MAGC(E2r + W2r, E2i + W2i); OUT[6] = MAGC(E2r - W2r, E2i - W2i); \
    OUT[3] = MAGC(E3r + W3r, E3i + W3i); OUT[7] = MAGC(E3r - W3r, E3i - W3i); \
  }
    REALCOL(0, mg0)
    REALCOL(1, mg4)
    CPLXCOL(2, 3, mg1)
    CPLXCOL(4, 5, mg2)
    CPLXCOL(6, 7, mg3)
    // hermitian expand + fftshift, packed bf16x8 into G A-fragment layout
    const int pb8 = p * 8, p7 = p & 7;
#pragma unroll
    for (int up = 0; up < 8; ++up) {
      union { unsigned short h[8]; short8 v; } pk;
#pragma unroll
      for (int vp = 0; vp < 8; ++vp) {
        const int u = (up + 4) & 7, vx = (vp + 4) & 7;
        float m;
        if (vx == 0)      m = mg0[(u <= 4) ? u : (8 - u)];
        else if (vx == 4) m = mg4[(u <= 4) ? u : (8 - u)];
        else if (vx == 1) m = mg1[u];
        else if (vx == 2) m = mg2[u];
        else if (vx == 3) m = mg3[u];
        else { const int uu = (8 - u) & 7;
               m = (vx == 5) ? mg3[uu] : (vx == 6) ? mg2[uu] : mg1[uu]; }
        pk.h[vp] = f2bf(m);
      }
      ldsX[pb8 + (up ^ p7)] = pk.v;
    }
  }
  __syncthreads();

  // ---- polar sampling + radial sum as MFMA: psum = mag(256x64) * G(64x16) ----
  {
    short8 gf0 = wsV[384 + lane];
    short8 gf1 = wsV[448 + lane];
    f32x4 ag[4];
#pragma unroll
    for (int pt = 0; pt < 4; ++pt) {
      int prow = (wave * 4 + pt) * 16 + (lane & 15);
      int p7 = prow & 7, pb = prow * 8;
      short8 a0 = ldsX[pb + (kcA ^ p7)];
      short8 a1 = ldsX[pb + ((kcA + 4) ^ p7)];
      f32x4 zf = (f32x4){0.f, 0.f, 0.f, 0.f};
      zf = __builtin_amdgcn_mfma_f32_16x16x32_bf16(a0, gf0, zf, 0, 0, 0);
      zf = __builtin_amdgcn_mfma_f32_16x16x32_bf16(a1, gf1, zf, 0, 0, 0);
      ag[pt] = zf;
    }
    float s0 = ag[0][0] + ag[0][1] + ag[0][2] + ag[0][3] +
               ag[1][0] + ag[1][1] + ag[1][2] + ag[1][3];
    float s1 = ag[2][0] + ag[2][1] + ag[2][2] + ag[2][3] +
               ag[3][0] + ag[3][1] + ag[3][2] + ag[3][3];
    s0 += __shfl_xor(s0, 16); s0 += __shfl_xor(s0, 32);
    s1 += __shfl_xor(s1, 16); s1 += __shfl_xor(s1, 32);
    float l0 = s0 * (1.0f / 256.0f), l1 = s1 * (1.0f / 256.0f);
    float m0 = l0, m1 = l1;
#pragma unroll
    for (int mk = 1; mk < 16; mk <<= 1) {
      m0 = fmaxf(m0, __shfl_xor(m0, mk));
      m1 = fmaxf(m1, __shfl_xor(m1, mk));
    }
    float e0 = expf(l0 - m0), e1 = expf(l1 - m1);
    float ss0 = e0, ss1 = e1;
#pragma unroll
    for (int mk = 1; mk < 16; mk <<= 1) {
      ss0 += __shfl_xor(ss0, mk);
      ss1 += __shfl_xor(ss1, mk);
    }
    float d0 = e0 / ss0, d1 = e1 / ss1;
    float h0 = -d0 * logf(fmaxf(d0, 1e-8f));
    float h1 = -d1 * logf(fmaxf(d1, 1e-8f));
#pragma unroll
    for (int mk = 1; mk < 16; mk <<= 1) {
      h0 += __shfl_xor(h0, mk);
      h1 += __shfl_xor(h1, mk);
    }
    float c0 = fminf(fmaxf(1.f - h0 * (1.0f / 2.7725887222397811f), 0.f), 1.f);
    float c1 = fminf(fmaxf(1.f - h1 * (1.0f / 2.7725887222397811f), 0.f), 1.f);
    if (lane < 16) {
      obuf[wave * 32 + lane] = d0;
      obuf[wave * 32 + 16 + lane] = d1;
    }
    if (lane == 0) {
      obuf[128 + wave * 2] = c0;
      obuf[128 + wave * 2 + 1] = c1;
    }
  }
  __syncthreads();

  if (tid < 128) {
    int t = tid >> 3, win = tid & 7;
    int wx = wxg * 8 + win;
    out[((size_t)(b * NT + t) * HG + hy) * WG + wx] = obuf[win * 16 + t];
  } else if (tid < 136) {
    int win = tid - 128;
    int wx = wxg * 8 + win;
    out[(size_t)NB * NT * HG * WG + ((size_t)b * HG + hy) * WG + wx] =
        obuf[128 + win];
  }
}

extern "C" void kernel_launch(void* const* d_in, const int* in_sizes, int n_in,
                              void* d_out, int out_size, void* d_ws,
                              size_t ws_size, hipStream_t stream) {
  (void)in_sizes; (void)n_in; (void)ws_size; (void)out_size;
  const float* x = (const float*)d_in[0];
  const float* Wp = (const float*)d_in[1];
  const float* bp = (const float*)d_in[2];
  unsigned short* ws = (unsigned short*)d_ws;
  float* out = (float*)d_out;
  lpp_setup<<<8, 256, 0, stream>>>(Wp, ws);
  lpp_main<<<NB * HG * 6, 256, 0, stream>>>(x, bp, ws, out);
}